// Round 14
// baseline (86.789 us; speedup 1.0000x reference)
//
#include <hip/hip_runtime.h>
#include <hip/hip_bf16.h>

#define B_N    8192
#define Z_N    10
#define IN_D   512
#define OUT_D  512
#define R_N    8
#define M_N    3
#define ALPHA  0.04419417382415922f   // 1/sqrt(512), SCALING=1 folded

// ---- grouped-GEMM geometry ----
#define NPC      16                    // nodes per chunk
#define BN       48                    // NPC * 3 columns
#define MAXCH    (B_N / NPC + Z_N)     // 522 worst-case chunks
#define BSTRIDE  1024                  // bf16 B_s stride + XOR swizzle (T2)

// B_s swizzle (r12-verified): col = byte>>10, 64B-block = byte>>6; XOR bits 4..6
__device__ __forceinline__ int swz(int byte) {
    return byte ^ ((((byte >> 10) ^ (byte >> 6)) & 7) << 4);
}
// fp32 T_s swizzle: col = byte>>11 (2048B stride), seg = byte>>8; XOR bits 4..6
__device__ __forceinline__ int swzf(int byte) {
    return byte ^ ((((byte >> 11) ^ (byte >> 8)) & 7) << 4);
}

// Wt tiled layout: [z][kt(16)][row(512)][32 ushorts = 64B covering k=kt*32..+31]

// ---- ws layout (bytes) ----
#define OFF_WT   0u
#define SZ_WT    (Z_N * OUT_D * IN_D * 2u)        // 5,242,880
#define OFF_PERM (OFF_WT + SZ_WT)
#define SZ_PERM  (B_N * 4u)
#define OFF_ZARR (OFF_PERM + SZ_PERM)
#define SZ_ZARR  (B_N * 4u)
#define OFF_PART (OFF_ZARR + SZ_ZARR)
#define SZ_PART  (32u * Z_N * 4u)
#define OFF_TOT  (OFF_PART + SZ_PART)
#define SZ_TOT   (Z_N * 4u)
#define WS_NEED  (OFF_TOT + SZ_TOT)

#define MERGE_BLOCKS (Z_N * OUT_D / 8)  // 640 (8 W-rows per block, A[z] in LDS)
#define ZHIST_BLOCKS (B_N / 256)        // 32

typedef __attribute__((ext_vector_type(8))) short short8v;
typedef __attribute__((ext_vector_type(4))) float float4v;
typedef __attribute__((ext_vector_type(4))) int   int4v;

__device__ __forceinline__ unsigned short f2bf(float f) {
    unsigned int x = __float_as_uint(f);
    x += 0x7fffu + ((x >> 16) & 1u);
    return (unsigned short)(x >> 16);
}
__device__ __forceinline__ float bfbits_lo(unsigned int u) { return __uint_as_float(u << 16); }
__device__ __forceinline__ float bfbits_hi(unsigned int u) { return __uint_as_float(u & 0xffff0000u); }

// packed f32x2 -> bf16x2 (RNE), single VALU op
__device__ __forceinline__ unsigned cvt_pk_bf16(float lo, float hi) {
    unsigned r;
    asm("v_cvt_pk_bf16_f32 %0, %1, %2" : "=v"(r) : "v"(lo), "v"(hi));
    return r;
}

// ---------------------------------------------------------------------------
// K1: fused  (a) W-merge -> bf16 TILED Wt, 8 rows/block with A[z] in LDS
//            (b) z-extract + per-block partial histogram (no global atomics)
// ---------------------------------------------------------------------------
__global__ __launch_bounds__(256) void prep_kernel(
    const float* __restrict__ weights, const float* __restrict__ lora_A,
    const float* __restrict__ lora_B, const float* __restrict__ attrs,
    unsigned short* __restrict__ Wt, int* __restrict__ zarr,
    int* __restrict__ part) {
    int bid = blockIdx.x;
    int tid = threadIdx.x;
    if (bid < MERGE_BLOCKS) {
        int r0 = bid * 8;                       // 8 rows, all same z (512%8==0)
        int z = r0 >> 9;
        __shared__ __align__(16) float4 a_s[R_N * 128];   // A[z] fp32, 16 KB
        const float4* A4 = reinterpret_cast<const float4*>(lora_A) + (size_t)z * (R_N * 128);
#pragma unroll
        for (int i = 0; i < 4; ++i) {
            int idx = tid + 256 * i;
            a_s[idx] = A4[idx];
        }
        int row = r0 + (tid >> 5);              // this thread's global row
        int o = row & 511;
        int ql = tid & 31;                      // lane's first q; q_j = ql + 32j
        float lb[R_N];
        const float* bp = lora_B + (size_t)row * R_N;
#pragma unroll
        for (int rr = 0; rr < R_N; ++rr) lb[rr] = bp[rr] * ALPHA;
        __syncthreads();

        const float4* w4 = reinterpret_cast<const float4*>(weights) + (size_t)row * 128;
#pragma unroll
        for (int j = 0; j < 4; ++j) {
            int q = ql + 32 * j;
            float4 wv = w4[q];
            float ax = wv.x * ALPHA, ay = wv.y * ALPHA;
            float az = wv.z * ALPHA, aw = wv.w * ALPHA;
#pragma unroll
            for (int rr = 0; rr < R_N; ++rr) {
                float4 av = a_s[rr * 128 + q];
                ax += av.x * lb[rr]; ay += av.y * lb[rr];
                az += av.z * lb[rr]; aw += av.w * lb[rr];
            }
            ushort4 o4;
            o4.x = f2bf(ax); o4.y = f2bf(ay); o4.z = f2bf(az); o4.w = f2bf(aw);
            size_t byte = ((size_t)z * 8192 + (size_t)(q >> 3) * 512 + o) * 64
                          + (size_t)(q & 7) * 8;
            *reinterpret_cast<ushort4*>(reinterpret_cast<char*>(Wt) + byte) = o4;
        }
    } else {
        __shared__ int h_s[Z_N];
        if (tid < Z_N) h_s[tid] = 0;
        __syncthreads();
        int bl = bid - MERGE_BLOCKS;
        int n = bl * 256 + tid;                 // exactly covers B_N
        const float* a = attrs + (size_t)n * Z_N;
        int z = 0;
#pragma unroll
        for (int zz = 1; zz < Z_N; ++zz)
            if (a[zz] > 0.5f) z = zz;
        zarr[n] = z;
        atomicAdd(&h_s[z], 1);
        __syncthreads();
        if (tid < Z_N) part[bl * Z_N + tid] = h_s[tid];
    }
}

// ---------------------------------------------------------------------------
// K2: deterministic scatter (no global atomics). Block b places its 256
// nodes; bases from partial histograms; block 0 also writes tot[z].
// ---------------------------------------------------------------------------
__global__ __launch_bounds__(256) void scatter_kernel(
    const int* __restrict__ zarr, const int* __restrict__ part,
    int* __restrict__ perm, int* __restrict__ tot) {
    __shared__ int lcnt[Z_N];
    __shared__ int base_s[Z_N];
    int b = blockIdx.x;
    int tid = threadIdx.x;
    if (tid < Z_N) lcnt[tid] = 0;
    __syncthreads();
    int n = b * 256 + tid;
    int z = zarr[n];
    int rank = atomicAdd(&lcnt[z], 1);   // LDS only; intra-z order irrelevant
    if (tid < Z_N) {
        int zq = tid, base = 0, tz = 0;
        for (int bb = 0; bb < ZHIST_BLOCKS; ++bb) {
            for (int zz = 0; zz < zq; ++zz) base += part[bb * Z_N + zz];
            int p = part[bb * Z_N + zq];
            if (bb < b) base += p;
            tz += p;
        }
        base_s[zq] = base;
        if (b == 0) tot[zq] = tz;
    }
    __syncthreads();
    perm[base_s[z] + rank] = n;
}

// ---------------------------------------------------------------------------
// K3: grouped GEMM (r9 structure) with DENSE-COALESCED t staging:
//  phase1: lane-consecutive float4 reads of t (1KB dense per instr) ->
//          fp32 scatter into swizzled 96KB T_s [col][k]
//  phase2: contiguous T_s reads -> cvt_pk -> swizzled 48KB bf16 B_s
//  K-loop: 8 waves x 64 rows x (4x3) mfma, A direct from tiled Wt
//  epilogue: single round through T_s (free after K starts) -> NT stores
// ---------------------------------------------------------------------------
__global__ __launch_bounds__(512) void gemm_kernel(
    const unsigned short* __restrict__ Wt, const float* __restrict__ t,
    const int* __restrict__ perm, const int* __restrict__ tot,
    float* __restrict__ out) {
    // bijective XCD-aware swizzle over [0, MAXCH)
    int orig = blockIdx.x;
    const int qq = MAXCH >> 3, r8 = MAXCH & 7;
    int xcd = orig & 7, off = orig >> 3;
    int chunk = (xcd < r8 ? xcd * (qq + 1) : r8 * (qq + 1) + (xcd - r8) * qq) + off;

    // chunk table recomputed from tot[10] (scalar, no arrays)
    int z = -1, ns = 0, nn = 0;
    {
        int cum = 0, cc = 0;
#pragma unroll
        for (int zz = 0; zz < Z_N; ++zz) {
            int hz = tot[zz];
            int czz = (hz + NPC - 1) / NPC;
            if (z < 0 && chunk < cc + czz) {
                z = zz;
                int j = (chunk - cc) * NPC;
                ns = cum + j;
                nn = (hz - j < NPC) ? (hz - j) : NPC;
            }
            cum += hz; cc += czz;
        }
        if (chunk >= cc) return;
    }

    __shared__ __align__(16) char T_s[BN * 2048];    // 98,304 B fp32 staging
    __shared__ __align__(16) char B_s[BN * BSTRIDE]; // 49,152 B bf16 operand
    __shared__ int node_ids[NPC];

    int tid = threadIdx.x;
    int lane = tid & 63, wid = tid >> 6;        // 8 waves
    int lrow = lane & 15, g = lane >> 4;
    int wrow = wid * 64;

    if (tid < NPC) node_ids[tid] = (tid < nn) ? perm[ns + tid] : -1;

    // ---- phase 1: dense-coalesced t reads -> fp32 scatter into T_s ----
    {
#pragma unroll
        for (int p = 0; p < 2; ++p) {
            int slot = wid * 2 + p;             // wave handles 2 node slots
            int node = (slot < nn) ? perm[ns + slot] : -1;
            const float4* tp = reinterpret_cast<const float4*>(t) + (size_t)(node < 0 ? 0 : node) * 384;
            int n3 = slot * 3;
#pragma unroll
            for (int i = 0; i < 6; ++i) {
                int f4i = lane + 64 * i;        // 0..383, lane-consecutive
                float4 v;
                if (node >= 0) v = tp[f4i];
                else { v.x = 0.f; v.y = 0.f; v.z = 0.f; v.w = 0.f; }
                float vv[4] = {v.x, v.y, v.z, v.w};
                int e0 = f4i * 4;
#pragma unroll
                for (int c = 0; c < 4; ++c) {
                    int e = e0 + c;             // < 1536
                    int k = e / 3;
                    int d = e - k * 3;
                    *reinterpret_cast<float*>(T_s + swzf((n3 + d) * 2048 + k * 4)) = vv[c];
                }
            }
        }
    }
    __syncthreads();

    // ---- phase 2: T_s fp32 -> cvt_pk -> B_s bf16 (48 cols x 8 segs) ----
    if (tid < 384) {
        int col = tid >> 3, seg = tid & 7;      // col 0..47, k-seg of 64
        float v[64];
#pragma unroll
        for (int i = 0; i < 16; ++i)
            *reinterpret_cast<float4v*>(&v[4 * i]) =
                *reinterpret_cast<const float4v*>(T_s + swzf(col * 2048 + (seg * 64 + 4 * i) * 4));
        unsigned u[32];
#pragma unroll
        for (int w = 0; w < 32; ++w) u[w] = cvt_pk_bf16(v[2 * w], v[2 * w + 1]);
#pragma unroll
        for (int q = 0; q < 8; ++q) {
            int4v x = (int4v){(int)u[4 * q], (int)u[4 * q + 1], (int)u[4 * q + 2], (int)u[4 * q + 3]};
            *reinterpret_cast<int4v*>(B_s + swz(col * 1024 + seg * 128 + 16 * q)) = x;
        }
    }
    __syncthreads();

    float4v acc[4][3];
#pragma unroll
    for (int mi = 0; mi < 4; ++mi)
#pragma unroll
        for (int ni = 0; ni < 3; ++ni) acc[mi][ni] = (float4v){0.f, 0.f, 0.f, 0.f};

    const unsigned short* aw = Wt + (size_t)z * 262144
                               + (size_t)(wrow + lrow) * 32 + (size_t)g * 8;

    for (int kt = 0; kt < 16; ++kt) {
        const unsigned short* ak = aw + kt * 16384;
        short8v a0 = *reinterpret_cast<const short8v*>(ak);
        short8v a1 = *reinterpret_cast<const short8v*>(ak + 512);
        short8v a2 = *reinterpret_cast<const short8v*>(ak + 1024);
        short8v a3 = *reinterpret_cast<const short8v*>(ak + 1536);
        short8v b[3];
#pragma unroll
        for (int ni = 0; ni < 3; ++ni) {
            int byte = (ni * 16 + lrow) * BSTRIDE + kt * 64 + g * 16;
            b[ni] = *reinterpret_cast<const short8v*>(B_s + swz(byte));
        }
#pragma unroll
        for (int ni = 0; ni < 3; ++ni) {
            acc[0][ni] = __builtin_amdgcn_mfma_f32_16x16x32_bf16(a0, b[ni], acc[0][ni], 0, 0, 0);
            acc[1][ni] = __builtin_amdgcn_mfma_f32_16x16x32_bf16(a1, b[ni], acc[1][ni], 0, 0, 0);
            acc[2][ni] = __builtin_amdgcn_mfma_f32_16x16x32_bf16(a2, b[ni], acc[2][ni], 0, 0, 0);
            acc[3][ni] = __builtin_amdgcn_mfma_f32_16x16x32_bf16(a3, b[ni], acc[3][ni], 0, 0, 0);
        }
    }

    // ---- epilogue: single round through T_s (512 rows x 48 cols fp32) ----
    // C/D layout: col = lane&15 (B col), row-in-frag = g*4+e (m89-verified)
    __syncthreads();                            // all B_s reads done; T_s free
#pragma unroll
    for (int mi = 0; mi < 4; ++mi)
#pragma unroll
        for (int ni = 0; ni < 3; ++ni) {
            int col = ni * 16 + lrow;
            int rl = wrow + mi * 16 + g * 4;
            *reinterpret_cast<float4v*>(T_s + swzf(col * 2048 + rl * 4)) = acc[mi][ni];
        }
    __syncthreads();
    // read out-linear: per node 384 float4; 16 nodes -> 6144 float4
#pragma unroll
    for (int it = 0; it < 12; ++it) {
        int fi = tid + it * 512;                // < 6144
        int node = fi / 384;
        int s = fi - node * 384;
        int nid = node_ids[node];
        if (nid < 0) continue;
        float4v v;
#pragma unroll
        for (int j = 0; j < 4; ++j) {
            int e = 4 * s + j;                  // < 1536
            int rl = e / 3;
            int d = e - 3 * rl;
            v[j] = *reinterpret_cast<const float*>(T_s + swzf((3 * node + d) * 2048 + rl * 4));
        }
        float* op = out + (size_t)nid * (OUT_D * M_N) + 4 * s;
        __builtin_nontemporal_store(v, reinterpret_cast<float4v*>(op));
    }
}

// ---------------------------------------------------------------------------
// Fallback (round-1 path) if ws is too small — row-major Wbf layout
// ---------------------------------------------------------------------------
__global__ __launch_bounds__(256) void merge_w_kernel(
    const float* __restrict__ weights, const float* __restrict__ lora_A,
    const float* __restrict__ lora_B, unsigned short* __restrict__ Wbf) {
    int zo = blockIdx.x;
    int z = zo >> 9;
    int o = zo & (OUT_D - 1);
    int tid = threadIdx.x;
    float lb[R_N];
    const float* bp = lora_B + ((size_t)z * OUT_D + o) * R_N;
#pragma unroll
    for (int r = 0; r < R_N; ++r) lb[r] = bp[r];
    const float* ap = lora_A + (size_t)z * R_N * IN_D;
    const float* wp = weights + ((size_t)z * OUT_D + o) * IN_D;
    unsigned short* op = Wbf + ((size_t)z * OUT_D + o) * IN_D;
    for (int i = tid; i < IN_D; i += 256) {
        float acc = wp[i];
#pragma unroll
        for (int r = 0; r < R_N; ++r) acc += ap[r * IN_D + i] * lb[r];
        op[i] = f2bf(acc * ALPHA);
    }
}

__global__ __launch_bounds__(256) void apply_kernel(
    const float* __restrict__ t, const float* __restrict__ attrs,
    const unsigned short* __restrict__ Wbf, float* __restrict__ out) {
    int b = blockIdx.x;
    int tid = threadIdx.x;
    const float* ab = attrs + (size_t)b * Z_N;
    int z = 0;
#pragma unroll
    for (int zz = 1; zz < Z_N; ++zz)
        if (ab[zz] > 0.5f) z = zz;
    __shared__ __align__(16) float t_s[IN_D * M_N];
    const float* tb = t + (size_t)b * (IN_D * M_N);
    for (int k = tid; k < IN_D * M_N; k += 256) t_s[k] = tb[k];
    __syncthreads();
    const unsigned short* w0 = Wbf + ((size_t)z * OUT_D + tid) * IN_D;
    const unsigned short* w1 = w0 + 256 * IN_D;
    float acc0[M_N] = {0.f, 0.f, 0.f};
    float acc1[M_N] = {0.f, 0.f, 0.f};
    for (int c = 0; c < IN_D; c += 8) {
        uint4 u0 = *reinterpret_cast<const uint4*>(w0 + c);
        uint4 u1 = *reinterpret_cast<const uint4*>(w1 + c);
        float wf0[8], wf1[8];
        unsigned int a0[4] = {u0.x, u0.y, u0.z, u0.w};
        unsigned int a1[4] = {u1.x, u1.y, u1.z, u1.w};
#pragma unroll
        for (int q = 0; q < 4; ++q) {
            wf0[2 * q] = bfbits_lo(a0[q]); wf0[2 * q + 1] = bfbits_hi(a0[q]);
            wf1[2 * q] = bfbits_lo(a1[q]); wf1[2 * q + 1] = bfbits_hi(a1[q]);
        }
        float tf[24];
        const float4* tv = reinterpret_cast<const float4*>(t_s + c * M_N);
#pragma unroll
        for (int q = 0; q < 6; ++q) {
            float4 v = tv[q];
            tf[4 * q] = v.x; tf[4 * q + 1] = v.y; tf[4 * q + 2] = v.z; tf[4 * q + 3] = v.w;
        }
#pragma unroll
        for (int cc = 0; cc < 8; ++cc)
#pragma unroll
            for (int d = 0; d < M_N; ++d) {
                acc0[d] += wf0[cc] * tf[cc * M_N + d];
                acc1[d] += wf1[cc] * tf[cc * M_N + d];
            }
    }
    float* ob = out + (size_t)b * (OUT_D * M_N);
#pragma unroll
    for (int d = 0; d < M_N; ++d) ob[tid * M_N + d] = acc0[d];
#pragma unroll
    for (int d = 0; d < M_N; ++d) ob[(tid + 256) * M_N + d] = acc1[d];
}

extern "C" void kernel_launch(void* const* d_in, const int* in_sizes, int n_in,
                              void* d_out, int out_size, void* d_ws, size_t ws_size,
                              hipStream_t stream) {
    const float* t       = (const float*)d_in[0];
    const float* attrs   = (const float*)d_in[1];
    const float* weights = (const float*)d_in[2];
    const float* lora_A  = (const float*)d_in[3];
    const float* lora_B  = (const float*)d_in[4];
    float* out = (float*)d_out;
    char* ws = (char*)d_ws;

    if (ws_size >= WS_NEED) {
        unsigned short* Wt = (unsigned short*)(ws + OFF_WT);
        int* perm = (int*)(ws + OFF_PERM);
        int* zarr = (int*)(ws + OFF_ZARR);
        int* part = (int*)(ws + OFF_PART);
        int* tot  = (int*)(ws + OFF_TOT);

        prep_kernel<<<MERGE_BLOCKS + ZHIST_BLOCKS, 256, 0, stream>>>(
            weights, lora_A, lora_B, attrs, Wt, zarr, part);
        scatter_kernel<<<ZHIST_BLOCKS, 256, 0, stream>>>(zarr, part, perm, tot);
        gemm_kernel<<<MAXCH, 512, 0, stream>>>(Wt, t, perm, tot, out);
    } else if (ws_size >= SZ_WT) {
        unsigned short* Wbf = (unsigned short*)(ws + OFF_WT);
        merge_w_kernel<<<Z_N * OUT_D, 256, 0, stream>>>(weights, lora_A, lora_B, Wbf);
        apply_kernel<<<B_N, 256, 0, stream>>>(t, attrs, Wbf, out);
    }
}

// Round 15
// 79.692 us; speedup vs baseline: 1.0891x; 1.0891x over previous
//
#include <hip/hip_runtime.h>
#include <hip/hip_bf16.h>

#define B_N    8192
#define Z_N    10
#define IN_D   512
#define OUT_D  512
#define R_N    8
#define M_N    3
#define ALPHA  0.04419417382415922f   // 1/sqrt(512), SCALING=1 folded

// ---- grouped-GEMM geometry ----
#define NPC      16                    // nodes per chunk
#define BN       48                    // NPC * 3 columns
#define MAXCH    (B_N / NPC + Z_N)     // 522 worst-case chunks
#define BSTRIDE  1040                  // r9-verified: 512*2 + 16 pad
#define GEMM_BLOCKS 256                // persistent: 1 block per CU

// Wt tiled layout: [z][kt(16)][row(512)][32 ushorts = 64B covering k=kt*32..+31]

// ---- ws layout (bytes) ----
#define OFF_WT   0u
#define SZ_WT    (Z_N * OUT_D * IN_D * 2u)        // 5,242,880
#define OFF_PERM (OFF_WT + SZ_WT)
#define SZ_PERM  (B_N * 4u)
#define OFF_ZARR (OFF_PERM + SZ_PERM)
#define SZ_ZARR  (B_N * 4u)
#define OFF_PART (OFF_ZARR + SZ_ZARR)
#define SZ_PART  (32u * Z_N * 4u)
#define OFF_TOT  (OFF_PART + SZ_PART)
#define SZ_TOT   (Z_N * 4u)
#define WS_NEED  (OFF_TOT + SZ_TOT)

#define MERGE_BLOCKS (Z_N * OUT_D / 8)  // 640 (8 W-rows per block, A[z] in LDS)
#define ZHIST_BLOCKS (B_N / 256)        // 32

typedef __attribute__((ext_vector_type(8))) short short8v;
typedef __attribute__((ext_vector_type(4))) float float4v;
typedef __attribute__((ext_vector_type(4))) int   int4v;

__device__ __forceinline__ unsigned short f2bf(float f) {
    unsigned int x = __float_as_uint(f);
    x += 0x7fffu + ((x >> 16) & 1u);
    return (unsigned short)(x >> 16);
}
__device__ __forceinline__ float bfbits_lo(unsigned int u) { return __uint_as_float(u << 16); }
__device__ __forceinline__ float bfbits_hi(unsigned int u) { return __uint_as_float(u & 0xffff0000u); }

// packed f32x2 -> bf16x2 (RNE), single VALU op
__device__ __forceinline__ unsigned cvt_pk_bf16(float lo, float hi) {
    unsigned r;
    asm("v_cvt_pk_bf16_f32 %0, %1, %2" : "=v"(r) : "v"(lo), "v"(hi));
    return r;
}

// chunk decode from tot[10]; returns total chunk count
__device__ __forceinline__ int decode_chunk(const int* __restrict__ tot, int chunk,
                                            int& z, int& ns, int& nn) {
    int cum = 0, cc = 0;
    z = -1; ns = 0; nn = 0;
#pragma unroll
    for (int zz = 0; zz < Z_N; ++zz) {
        int hz = tot[zz];
        int czz = (hz + NPC - 1) / NPC;
        if (z < 0 && chunk < cc + czz) {
            z = zz;
            int j = (chunk - cc) * NPC;
            ns = cum + j;
            nn = (hz - j < NPC) ? (hz - j) : NPC;
        }
        cum += hz; cc += czz;
    }
    return cc;
}

// ---------------------------------------------------------------------------
// K1: fused  (a) W-merge -> bf16 TILED Wt, 8 rows/block with A[z] in LDS
//            (b) z-extract + per-block partial histogram (no global atomics)
// ---------------------------------------------------------------------------
__global__ __launch_bounds__(256) void prep_kernel(
    const float* __restrict__ weights, const float* __restrict__ lora_A,
    const float* __restrict__ lora_B, const float* __restrict__ attrs,
    unsigned short* __restrict__ Wt, int* __restrict__ zarr,
    int* __restrict__ part) {
    int bid = blockIdx.x;
    int tid = threadIdx.x;
    if (bid < MERGE_BLOCKS) {
        int r0 = bid * 8;                       // 8 rows, all same z (512%8==0)
        int z = r0 >> 9;
        __shared__ __align__(16) float4 a_s[R_N * 128];   // A[z] fp32, 16 KB
        const float4* A4 = reinterpret_cast<const float4*>(lora_A) + (size_t)z * (R_N * 128);
#pragma unroll
        for (int i = 0; i < 4; ++i) {
            int idx = tid + 256 * i;
            a_s[idx] = A4[idx];
        }
        int row = r0 + (tid >> 5);              // this thread's global row
        int o = row & 511;
        int ql = tid & 31;                      // lane's first q; q_j = ql + 32j
        float lb[R_N];
        const float* bp = lora_B + (size_t)row * R_N;
#pragma unroll
        for (int rr = 0; rr < R_N; ++rr) lb[rr] = bp[rr] * ALPHA;
        __syncthreads();

        const float4* w4 = reinterpret_cast<const float4*>(weights) + (size_t)row * 128;
#pragma unroll
        for (int j = 0; j < 4; ++j) {
            int q = ql + 32 * j;
            float4 wv = w4[q];
            float ax = wv.x * ALPHA, ay = wv.y * ALPHA;
            float az = wv.z * ALPHA, aw = wv.w * ALPHA;
#pragma unroll
            for (int rr = 0; rr < R_N; ++rr) {
                float4 av = a_s[rr * 128 + q];
                ax += av.x * lb[rr]; ay += av.y * lb[rr];
                az += av.z * lb[rr]; aw += av.w * lb[rr];
            }
            ushort4 o4;
            o4.x = f2bf(ax); o4.y = f2bf(ay); o4.z = f2bf(az); o4.w = f2bf(aw);
            size_t byte = ((size_t)z * 8192 + (size_t)(q >> 3) * 512 + o) * 64
                          + (size_t)(q & 7) * 8;
            *reinterpret_cast<ushort4*>(reinterpret_cast<char*>(Wt) + byte) = o4;
        }
    } else {
        __shared__ int h_s[Z_N];
        if (tid < Z_N) h_s[tid] = 0;
        __syncthreads();
        int bl = bid - MERGE_BLOCKS;
        int n = bl * 256 + tid;                 // exactly covers B_N
        const float* a = attrs + (size_t)n * Z_N;
        int z = 0;
#pragma unroll
        for (int zz = 1; zz < Z_N; ++zz)
            if (a[zz] > 0.5f) z = zz;
        zarr[n] = z;
        atomicAdd(&h_s[z], 1);
        __syncthreads();
        if (tid < Z_N) part[bl * Z_N + tid] = h_s[tid];
    }
}

// ---------------------------------------------------------------------------
// K2: deterministic scatter (no global atomics). Block b places its 256
// nodes; bases from partial histograms; block 0 also writes tot[z].
// ---------------------------------------------------------------------------
__global__ __launch_bounds__(256) void scatter_kernel(
    const int* __restrict__ zarr, const int* __restrict__ part,
    int* __restrict__ perm, int* __restrict__ tot) {
    __shared__ int lcnt[Z_N];
    __shared__ int base_s[Z_N];
    int b = blockIdx.x;
    int tid = threadIdx.x;
    if (tid < Z_N) lcnt[tid] = 0;
    __syncthreads();
    int n = b * 256 + tid;
    int z = zarr[n];
    int rank = atomicAdd(&lcnt[z], 1);   // LDS only; intra-z order irrelevant
    if (tid < Z_N) {
        int zq = tid, base = 0, tz = 0;
        for (int bb = 0; bb < ZHIST_BLOCKS; ++bb) {
            for (int zz = 0; zz < zq; ++zz) base += part[bb * Z_N + zz];
            int p = part[bb * Z_N + zq];
            if (bb < b) base += p;
            tz += p;
        }
        base_s[zq] = base;
        if (b == 0) tot[zq] = tz;
    }
    __syncthreads();
    perm[base_s[z] + rank] = n;
}

// ---------------------------------------------------------------------------
// K3: PERSISTENT grouped GEMM with cross-chunk pipelining.
// grid = 256 (1 block/CU); block handles chunks {bid, bid+256, ...}.
// Per iter: issue NEXT chunk's t-loads (regs, sched_barrier-pinned) ->
// K-loop current (r9-verified) -> write next B_s (hides t latency) ->
// epilogue current (r9's coalesced LDS->NT-store path). Double-buffered B_s.
// ---------------------------------------------------------------------------
__global__ __launch_bounds__(512, 2) void gemm_kernel(
    const unsigned short* __restrict__ Wt, const float* __restrict__ t,
    const int* __restrict__ perm, const int* __restrict__ tot,
    float* __restrict__ out) {
    __shared__ __align__(16) char B_s[2][BN * BSTRIDE];   // 2 x 49,920 B
    __shared__ int node_ids[2][NPC];

    int tid = threadIdx.x;
    int lane = tid & 63, wid = tid >> 6;
    int lrow = lane & 15, g = lane >> 4;
    int wrow = wid * 64;
    int n_slot = tid >> 5, grp = tid & 31;      // staging coords (r9 geometry)

    int z, ns, nn;
    int cc = decode_chunk(tot, blockIdx.x, z, ns, nn);
    if ((int)blockIdx.x >= cc) return;

    int cur = 0;

    // ---- prologue: stage chunk bid into buffer 0 ----
    {
        int node = (n_slot < nn) ? perm[ns + n_slot] : -1;
        const float4* tp = reinterpret_cast<const float4*>(t)
                         + (size_t)(node < 0 ? 0 : node) * 384 + grp * 12;
        float f[48];
#pragma unroll
        for (int j = 0; j < 12; ++j) {
            float4 v = (node >= 0) ? tp[j] : make_float4(0.f, 0.f, 0.f, 0.f);
            f[4 * j] = v.x; f[4 * j + 1] = v.y; f[4 * j + 2] = v.z; f[4 * j + 3] = v.w;
        }
        if (tid < NPC) node_ids[0][tid] = (tid < nn) ? perm[ns + tid] : -1;
#pragma unroll
        for (int d = 0; d < 3; ++d) {
            unsigned u[8];
#pragma unroll
            for (int m = 0; m < 8; ++m)
                u[m] = cvt_pk_bf16(f[3 * (2 * m) + d], f[3 * (2 * m + 1) + d]);
            int4v v0 = (int4v){(int)u[0], (int)u[1], (int)u[2], (int)u[3]};
            int4v v1 = (int4v){(int)u[4], (int)u[5], (int)u[6], (int)u[7]};
            char* base = B_s[0] + (n_slot * 3 + d) * BSTRIDE + grp * 32;
            *reinterpret_cast<int4v*>(base)      = v0;
            *reinterpret_cast<int4v*>(base + 16) = v1;
        }
    }
    __syncthreads();

    for (int c = blockIdx.x; c < cc; c += GEMM_BLOCKS) {
        // ---- issue NEXT chunk's t-loads into registers (pinned early) ----
        int c2 = c + GEMM_BLOCKS;
        bool has_next = (c2 < cc);
        int z2 = z, ns2 = ns, nn2 = nn;
        float4 f4[12];
        int node2 = -1;
        if (has_next) {
            decode_chunk(tot, c2, z2, ns2, nn2);
            node2 = (n_slot < nn2) ? perm[ns2 + n_slot] : -1;
            const float4* tp = reinterpret_cast<const float4*>(t)
                             + (size_t)(node2 < 0 ? 0 : node2) * 384 + grp * 12;
#pragma unroll
            for (int j = 0; j < 12; ++j)
                f4[j] = (node2 >= 0) ? tp[j] : make_float4(0.f, 0.f, 0.f, 0.f);
            if (tid < NPC) node_ids[cur ^ 1][tid] = (tid < nn2) ? perm[ns2 + tid] : -1;
        }
        __builtin_amdgcn_sched_barrier(0);      // keep loads issued above

        // ---- K-loop (r9-verified body) on B_s[cur] ----
        float4v acc[4][3];
#pragma unroll
        for (int mi = 0; mi < 4; ++mi)
#pragma unroll
            for (int ni = 0; ni < 3; ++ni) acc[mi][ni] = (float4v){0.f, 0.f, 0.f, 0.f};

        const char* bp0 = B_s[cur] + lrow * BSTRIDE + g * 16;
        const unsigned short* aw = Wt + (size_t)z * 262144
                                   + (size_t)(wrow + lrow) * 32 + (size_t)g * 8;

        for (int kt = 0; kt < 16; ++kt) {
            const unsigned short* ak = aw + kt * 16384;
            short8v a0 = *reinterpret_cast<const short8v*>(ak);
            short8v a1 = *reinterpret_cast<const short8v*>(ak + 512);
            short8v a2 = *reinterpret_cast<const short8v*>(ak + 1024);
            short8v a3 = *reinterpret_cast<const short8v*>(ak + 1536);
            short8v b0 = *reinterpret_cast<const short8v*>(bp0 + 0 * 16 * BSTRIDE + kt * 64);
            short8v b1 = *reinterpret_cast<const short8v*>(bp0 + 1 * 16 * BSTRIDE + kt * 64);
            short8v b2 = *reinterpret_cast<const short8v*>(bp0 + 2 * 16 * BSTRIDE + kt * 64);
            acc[0][0] = __builtin_amdgcn_mfma_f32_16x16x32_bf16(a0, b0, acc[0][0], 0, 0, 0);
            acc[0][1] = __builtin_amdgcn_mfma_f32_16x16x32_bf16(a0, b1, acc[0][1], 0, 0, 0);
            acc[0][2] = __builtin_amdgcn_mfma_f32_16x16x32_bf16(a0, b2, acc[0][2], 0, 0, 0);
            acc[1][0] = __builtin_amdgcn_mfma_f32_16x16x32_bf16(a1, b0, acc[1][0], 0, 0, 0);
            acc[1][1] = __builtin_amdgcn_mfma_f32_16x16x32_bf16(a1, b1, acc[1][1], 0, 0, 0);
            acc[1][2] = __builtin_amdgcn_mfma_f32_16x16x32_bf16(a1, b2, acc[1][2], 0, 0, 0);
            acc[2][0] = __builtin_amdgcn_mfma_f32_16x16x32_bf16(a2, b0, acc[2][0], 0, 0, 0);
            acc[2][1] = __builtin_amdgcn_mfma_f32_16x16x32_bf16(a2, b1, acc[2][1], 0, 0, 0);
            acc[2][2] = __builtin_amdgcn_mfma_f32_16x16x32_bf16(a2, b2, acc[2][2], 0, 0, 0);
            acc[3][0] = __builtin_amdgcn_mfma_f32_16x16x32_bf16(a3, b0, acc[3][0], 0, 0, 0);
            acc[3][1] = __builtin_amdgcn_mfma_f32_16x16x32_bf16(a3, b1, acc[3][1], 0, 0, 0);
            acc[3][2] = __builtin_amdgcn_mfma_f32_16x16x32_bf16(a3, b2, acc[3][2], 0, 0, 0);
        }

        // ---- write next B into the other buffer (t latency already hidden) ----
        if (has_next) {
            float f[48];
#pragma unroll
            for (int j = 0; j < 12; ++j) {
                f[4 * j] = f4[j].x; f[4 * j + 1] = f4[j].y;
                f[4 * j + 2] = f4[j].z; f[4 * j + 3] = f4[j].w;
            }
#pragma unroll
            for (int d = 0; d < 3; ++d) {
                unsigned u[8];
#pragma unroll
                for (int m = 0; m < 8; ++m)
                    u[m] = cvt_pk_bf16(f[3 * (2 * m) + d], f[3 * (2 * m + 1) + d]);
                int4v v0 = (int4v){(int)u[0], (int)u[1], (int)u[2], (int)u[3]};
                int4v v1 = (int4v){(int)u[4], (int)u[5], (int)u[6], (int)u[7]};
                char* base = B_s[cur ^ 1] + (n_slot * 3 + d) * BSTRIDE + grp * 32;
                *reinterpret_cast<int4v*>(base)      = v0;
                *reinterpret_cast<int4v*>(base + 16) = v1;
            }
        }
        __syncthreads();   // all K-reads of B_s[cur] done; next-B written

        // ---- epilogue (r9-verified): acc -> B_s[cur] scratch -> NT stores ----
        // C/D layout: col = lane&15 (B col), row-in-frag = g*4+e (m89-verified)
#pragma unroll
        for (int r = 0; r < 2; ++r) {
            if ((wid >> 2) == r) {
                int widr = wid & 3;
#pragma unroll
                for (int mi = 0; mi < 4; ++mi)
#pragma unroll
                    for (int ni = 0; ni < 3; ++ni) {
                        int col = ni * 16 + lrow;
                        int rl = widr * 64 + mi * 16 + g * 4;
                        *reinterpret_cast<float4v*>(B_s[cur] + col * BSTRIDE + rl * 4) = acc[mi][ni];
                    }
            }
            __syncthreads();
#pragma unroll
            for (int it = 0; it < 6; ++it) {
                int fi = tid + it * 512;          // < 3072
                int node = fi / 192;
                int s = fi - node * 192;
                int nid = node_ids[cur][node];
                if (nid < 0) continue;
                float4v v;
#pragma unroll
                for (int j = 0; j < 4; ++j) {
                    int e = 4 * s + j;            // e < 768
                    int rl = e / 3;
                    int d = e - 3 * rl;
                    v[j] = *reinterpret_cast<const float*>(
                        B_s[cur] + (3 * node + d) * BSTRIDE + rl * 4);
                }
                float* op = out + (size_t)nid * (OUT_D * M_N) + r * 768 + 4 * s;
                __builtin_nontemporal_store(v, reinterpret_cast<float4v*>(op));
            }
            __syncthreads();   // reads done before next scratch write / reuse
        }

        // ---- advance ----
        z = z2; ns = ns2; nn = nn2;
        cur ^= 1;
    }
}

// ---------------------------------------------------------------------------
// Fallback (round-1 path) if ws is too small — row-major Wbf layout
// ---------------------------------------------------------------------------
__global__ __launch_bounds__(256) void merge_w_kernel(
    const float* __restrict__ weights, const float* __restrict__ lora_A,
    const float* __restrict__ lora_B, unsigned short* __restrict__ Wbf) {
    int zo = blockIdx.x;
    int z = zo >> 9;
    int o = zo & (OUT_D - 1);
    int tid = threadIdx.x;
    float lb[R_N];
    const float* bp = lora_B + ((size_t)z * OUT_D + o) * R_N;
#pragma unroll
    for (int r = 0; r < R_N; ++r) lb[r] = bp[r];
    const float* ap = lora_A + (size_t)z * R_N * IN_D;
    const float* wp = weights + ((size_t)z * OUT_D + o) * IN_D;
    unsigned short* op = Wbf + ((size_t)z * OUT_D + o) * IN_D;
    for (int i = tid; i < IN_D; i += 256) {
        float acc = wp[i];
#pragma unroll
        for (int r = 0; r < R_N; ++r) acc += ap[r * IN_D + i] * lb[r];
        op[i] = f2bf(acc * ALPHA);
    }
}

__global__ __launch_bounds__(256) void apply_kernel(
    const float* __restrict__ t, const float* __restrict__ attrs,
    const unsigned short* __restrict__ Wbf, float* __restrict__ out) {
    int b = blockIdx.x;
    int tid = threadIdx.x;
    const float* ab = attrs + (size_t)b * Z_N;
    int z = 0;
#pragma unroll
    for (int zz = 1; zz < Z_N; ++zz)
        if (ab[zz] > 0.5f) z = zz;
    __shared__ __align__(16) float t_s[IN_D * M_N];
    const float* tb = t + (size_t)b * (IN_D * M_N);
    for (int k = tid; k < IN_D * M_N; k += 256) t_s[k] = tb[k];
    __syncthreads();
    const unsigned short* w0 = Wbf + ((size_t)z * OUT_D + tid) * IN_D;
    const unsigned short* w1 = w0 + 256 * IN_D;
    float acc0[M_N] = {0.f, 0.f, 0.f};
    float acc1[M_N] = {0.f, 0.f, 0.f};
    for (int c = 0; c < IN_D; c += 8) {
        uint4 u0 = *reinterpret_cast<const uint4*>(w0 + c);
        uint4 u1 = *reinterpret_cast<const uint4*>(w1 + c);
        float wf0[8], wf1[8];
        unsigned int a0[4] = {u0.x, u0.y, u0.z, u0.w};
        unsigned int a1[4] = {u1.x, u1.y, u1.z, u1.w};
#pragma unroll
        for (int q = 0; q < 4; ++q) {
            wf0[2 * q] = bfbits_lo(a0[q]); wf0[2 * q + 1] = bfbits_hi(a0[q]);
            wf1[2 * q] = bfbits_lo(a1[q]); wf1[2 * q + 1] = bfbits_hi(a1[q]);
        }
        float tf[24];
        const float4* tv = reinterpret_cast<const float4*>(t_s + c * M_N);
#pragma unroll
        for (int q = 0; q < 6; ++q) {
            float4 v = tv[q];
            tf[4 * q] = v.x; tf[4 * q + 1] = v.y; tf[4 * q + 2] = v.z; tf[4 * q + 3] = v.w;
        }
#pragma unroll
        for (int cc = 0; cc < 8; ++cc)
#pragma unroll
            for (int d = 0; d < M_N; ++d) {
                acc0[d] += wf0[cc] * tf[cc * M_N + d];
                acc1[d] += wf1[cc] * tf[cc * M_N + d];
            }
    }
    float* ob = out + (size_t)b * (OUT_D * M_N);
#pragma unroll
    for (int d = 0; d < M_N; ++d) ob[tid * M_N + d] = acc0[d];
#pragma unroll
    for (int d = 0; d < M_N; ++d) ob[(tid + 256) * M_N + d] = acc1[d];
}

extern "C" void kernel_launch(void* const* d_in, const int* in_sizes, int n_in,
                              void* d_out, int out_size, void* d_ws, size_t ws_size,
                              hipStream_t stream) {
    const float* t       = (const float*)d_in[0];
    const float* attrs   = (const float*)d_in[1];
    const float* weights = (const float*)d_in[2];
    const float* lora_A  = (const float*)d_in[3];
    const float* lora_B  = (const float*)d_in[4];
    float* out = (float*)d_out;
    char* ws = (char*)d_ws;

    if (ws_size >= WS_NEED) {
        unsigned short* Wt = (unsigned short*)(ws + OFF_WT);
        int* perm = (int*)(ws + OFF_PERM);
        int* zarr = (int*)(ws + OFF_ZARR);
        int* part = (int*)(ws + OFF_PART);
        int* tot  = (int*)(ws + OFF_TOT);

        prep_kernel<<<MERGE_BLOCKS + ZHIST_BLOCKS, 256, 0, stream>>>(
            weights, lora_A, lora_B, attrs, Wt, zarr, part);
        scatter_kernel<<<ZHIST_BLOCKS, 256, 0, stream>>>(zarr, part, perm, tot);
        gemm_kernel<<<GEMM_BLOCKS, 512, 0, stream>>>(Wt, t, perm, tot, out);
    } else if (ws_size >= SZ_WT) {
        unsigned short* Wbf = (unsigned short*)(ws + OFF_WT);
        merge_w_kernel<<<Z_N * OUT_D, 256, 0, stream>>>(weights, lora_A, lora_B, Wbf);
        apply_kernel<<<B_N, 256, 0, stream>>>(t, attrs, Wbf, out);
    }
}